// Round 15
// baseline (70.740 us; speedup 1.0000x reference)
//
#include <hip/hip_runtime.h>

#define NENT 100000
#define NREL 32
#define DIM  128
#define NB   2048

typedef short s8v __attribute__((ext_vector_type(8)));
typedef float f4v __attribute__((ext_vector_type(4)));

__device__ __forceinline__ unsigned short f2bf(float x){
  unsigned u = __float_as_uint(x);
  return (unsigned short)((u + 0x7fffu + ((u>>16)&1u)) >> 16);
}
__device__ __forceinline__ float bf2f(unsigned short u){
  return __uint_as_float(((unsigned)u) << 16);
}
__device__ __forceinline__ float lo2f(unsigned p){ return __uint_as_float(p << 16); }
__device__ __forceinline__ float hi2f(unsigned p){ return __uint_as_float(p & 0xffff0000u); }
__device__ __forceinline__ float leakyf(float x){ return x > 0.f ? x : 0.2f*x; }

#define GATH_BLKS  512
#define SCORE_BLKS 512
#define SCALE_BLKS 12500   // 8 rows per 512-thr block

// ---------------- gathprep: gather (4 b/block) ∪ weight-prep — feeds k_scorescale
__global__ __launch_bounds__(256) void k_gathprep(const int* __restrict__ eidx,
                                                  const int* __restrict__ adjE,
                                                  const int* __restrict__ adjR,
                                                  const float* __restrict__ ent,
                                                  const float* __restrict__ rel,
                                                  const float* __restrict__ A1,
                                                  const float* __restrict__ A2,
                                                  const float* __restrict__ Wxw,
                                                  const float* __restrict__ W1w,
                                                  const float* __restrict__ W2w,
                                                  float* __restrict__ Pg,
                                                  unsigned short* __restrict__ A1Lf,
                                                  unsigned short* __restrict__ A2f,
                                                  unsigned short* __restrict__ WxF,
                                                  unsigned short* __restrict__ W1F,
                                                  unsigned short* __restrict__ W2F,
                                                  int* __restrict__ E1g, int* __restrict__ E2g,
                                                  int* __restrict__ R0g, int* __restrict__ R1g,
                                                  unsigned* __restrict__ ANb,
                                                  float* __restrict__ Hb, float* __restrict__ S1,
                                                  float* __restrict__ out){
  int t = threadIdx.x;
  __shared__ float srn[2][128];
  __shared__ float red[2][2];
  if (blockIdx.x < GATH_BLKS){
    int w = t>>6, l = t&63;
    int b = blockIdx.x*4 + w;
    int idx = eidx[b];
    int e1 = 0;
    if (l < 16){
      e1 = adjE[idx*16 + l];
      E1g[b*16+l] = e1;
      R0g[b*16+l] = adjR[idx*16 + l];
    }
    int esrc = __shfl(e1, l>>2);
    int4 e2 = *(const int4*)(adjE + (size_t)esrc*16 + (l&3)*4);
    int4 r1 = *(const int4*)(adjR + (size_t)esrc*16 + (l&3)*4);
    *(int4*)(E2g + (size_t)b*256 + l*4) = e2;
    *(int4*)(R1g + (size_t)b*256 + l*4) = r1;
    float2 hv = *(const float2*)(ent + (size_t)idx*128 + 2*l);
    float2 rv[16];
#pragma unroll
    for (int i=0;i<16;i++){
      int e = __shfl(e1, i);
      rv[i] = *(const float2*)(ent + (size_t)e*128 + 2*l);
    }
    float ssh = hv.x*hv.x + hv.y*hv.y;
    for (int m=1;m<64;m<<=1) ssh += __shfl_xor(ssh, m);
    float sch = fminf(1.f, 1.f/(sqrtf(ssh) + 1e-7f));
    hv.x *= sch; hv.y *= sch;
    float sx = 0.f, sy = 0.f;
#pragma unroll
    for (int i=0;i<16;i++){
      float ss = rv[i].x*rv[i].x + rv[i].y*rv[i].y;
      for (int m=1;m<64;m<<=1) ss += __shfl_xor(ss, m);
      float sc = fminf(1.f, 1.f/(sqrtf(ss) + 1e-7f));
      sx += sc*rv[i].x; sy += sc*rv[i].y;
    }
    ANb[((size_t)b*2 + 0)*64 + l] = (unsigned)f2bf(hv.x) | ((unsigned)f2bf(hv.y) << 16);
    ANb[((size_t)b*2 + 1)*64 + l] = (unsigned)f2bf(sx) | ((unsigned)f2bf(sy) << 16);
    *(float2*)(Hb + (size_t)b*128 + 2*l) = hv;
    *(float2*)(out + (size_t)b*640 + 512 + 2*l) = hv;
    float2 sv = { sx, sy };
    *(float2*)(S1 + (size_t)b*128 + 2*l) = sv;
    return;
  }
  int half = t>>7, tt = t&127;
  int blk = (blockIdx.x - GATH_BLKS)*2 + half;
  if (blk < 32){
    int r = blk;
    float v = rel[r*128 + tt];
    float ss = v*v;
    for (int m=1;m<64;m<<=1) ss += __shfl_xor(ss, m);
    if ((tt&63)==0) red[half][tt>>6] = ss;
    __syncthreads();
    float nrm = sqrtf(red[half][0]+red[half][1]);
    float f = fminf(1.f, 1.f/(nrm + 1e-7f));
    srn[half][tt] = v*f;
    __syncthreads();
    const float4* ar = (const float4*)(A1 + tt*256 + 128);
    float acc = 0.f;
#pragma unroll
    for (int k4=0;k4<32;k4++){
      float4 a = ar[k4];
      acc += a.x*srn[half][k4*4] + a.y*srn[half][k4*4+1]
           + a.z*srn[half][k4*4+2] + a.w*srn[half][k4*4+3];
    }
    Pg[r*128 + tt] = acc;
  } else if (blk < 64){
    int bb = blk - 32;
    int fid = bb*64 + (tt>>1);
    int hf = tt&1;
    int lane = fid & 63, kc = (fid>>6)&3, dt = fid>>8;
    int d = dt*16 + (lane&15);
    int kb = kc*32 + ((lane>>4)&3)*8 + hf*4;
#pragma unroll
    for (int i=0;i<4;i++)
      A2f[fid*8 + hf*4 + i] = f2bf(A2[d*128 + kb + i]);
  } else if (blk < 96){
    int bb = blk - 64;
    int fid = bb*64 + (tt>>1);
    int hf = tt&1;
    int lane = fid & 63, kc = (fid>>6)&3, dt = fid>>8;
    int d = dt*16 + (lane&15);
    int kb = kc*32 + ((lane>>4)&3)*8 + hf*4;
#pragma unroll
    for (int i=0;i<4;i++)
      A1Lf[fid*8 + hf*4 + i] = f2bf(A1[d*256 + kb + i]);
  } else if (blk < 160){
    int fid = (blk-96)*128 + tt;
    int l = fid&63, kc = (fid>>6)&3, nt = (fid>>8)&15, iter = (fid>>12)&1;
    int n = nt*16 + (l&15);
    int k = kc*32 + ((l>>4)&3)*8;
    const float* src = Wxw + ((size_t)((iter*2 + (n>>7))*128 + (n&127)))*128 + k;
#pragma unroll
    for (int j=0;j<8;j++) WxF[(size_t)fid*8 + j] = f2bf(src[j]);
  } else if (blk < 224){
    int fid = (blk-160)*128 + tt;
    int l = fid&63, kc = (fid>>6)&7, nt = (fid>>9)&15;
    int n = nt*16 + (l&15);
    int k = kc*32 + ((l>>4)&3)*8;
#pragma unroll
    for (int j=0;j<8;j++) W1F[(size_t)fid*8 + j] = f2bf(W1w[(size_t)n*256 + k + j]);
  } else {
    int fid = (blk-224)*128 + tt;
    int l = fid&63, kc = (fid>>6)&7, nt = (fid>>9)&15;
    int n = nt*16 + (l&15);
    int k = kc*32 + ((l>>4)&3)*8;
#pragma unroll
    for (int j=0;j<8;j++) W2F[(size_t)fid*8 + j] = f2bf(W2w[(size_t)n*256 + k + j]);
  }
}

// ---------------- scorescale: scores (blocks < SCORE_BLKS) ∥ ent→entF scan (rest)
__global__ __launch_bounds__(512) void k_scorescale(const unsigned* __restrict__ ANb,
                                                    const unsigned short* __restrict__ A1Lf,
                                                    const float* __restrict__ Pg,
                                                    const unsigned short* __restrict__ A2f,
                                                    const float* __restrict__ A3,
                                                    const int* __restrict__ R0g,
                                                    const int* __restrict__ R1g,
                                                    const float* __restrict__ ent,
                                                    unsigned short* __restrict__ entF,
                                                    float* __restrict__ W0g,
                                                    float* __restrict__ W1g){
  int t = threadIdx.x, l = t&63, w = t>>6;
  if (blockIdx.x >= SCORE_BLKS){
    int row = (blockIdx.x - SCORE_BLKS)*8 + w;
    if (row >= NENT) return;
    float2 v = *(const float2*)(ent + (size_t)row*128 + 2*l);
    float ss = v.x*v.x + v.y*v.y;
    for (int m=1;m<64;m<<=1) ss += __shfl_xor(ss, m);
    float sc = fminf(1.f, 1.f/(sqrtf(ss) + 1e-7f));
    int p8 = __builtin_amdgcn_cvt_pk_fp8_f32(sc*v.x, sc*v.y, 0, false);
    entF[(size_t)row*64 + l] = (unsigned short)p8;
    return;
  }
  int blk = blockIdx.x;              // 4 b per block
  __shared__ __align__(16) unsigned short sA2f[2048*8];  // 32 KB
  __shared__ __align__(16) unsigned sAN[16*64];
  __shared__ float sC[8][132];
  __shared__ float sSC[4][64];

  { // stage A2f + anchors
    const uint4* src = (const uint4*)A2f;
    uint4* dst = (uint4*)sA2f;
#pragma unroll
    for (int i=0;i<4;i++) dst[t + i*512] = src[t + i*512];
    if (t < 256){
      int row = t>>4, seg = t&15;
      uint4 v = {0u,0u,0u,0u};
      if (row < 8) v = *(const uint4*)(ANb + ((size_t)blk*8 + row)*64 + seg*4);
      *(uint4*)((char*)sAN + ((row*256 + seg*16) ^ ((row&7)<<4))) = v;
    }
  }
  __syncthreads();

  int cl = l&15, kg = l>>4;
  { // G1: c = A1L @ anchors ; wave w -> dt = w
    s8v bf[4];
#pragma unroll
    for (int kc=0;kc<4;kc++)
      bf[kc] = *(const s8v*)((const char*)sAN + ((cl*256 + (kc*32+kg*8)*2) ^ ((cl&7)<<4)));
    int dt = w;
    f4v acc = {0.f,0.f,0.f,0.f};
#pragma unroll
    for (int kc=0;kc<4;kc++){
      s8v af = *(const s8v*)(A1Lf + ((size_t)((dt*4+kc)*64 + l))*8);
      acc = __builtin_amdgcn_mfma_f32_16x16x32_bf16(af, bf[kc], acc, 0, 0, 0);
    }
    if (cl < 8){
#pragma unroll
      for (int r=0;r<4;r++) sC[cl][dt*16 + kg*4 + r] = acc[r];
    }
  }
  __syncthreads();

  { // G2: wave w -> anchor ci = w ; cc splits relations
    s8v bfr0[4], bfr1[4];
#pragma unroll
    for (int cc=0; cc<2; cc++){
      int ci = w;
      int rr = cc*16 + cl;
      s8v* bfr = cc ? bfr1 : bfr0;
#pragma unroll
      for (int kc=0;kc<4;kc++){
        int k0 = kc*32 + kg*8;
        float4 pa = *(const float4*)(Pg + rr*128 + k0);
        float4 pb = *(const float4*)(Pg + rr*128 + k0 + 4);
        bfr[kc][0] = (short)f2bf(fmaxf(sC[ci][k0+0]+pa.x, 0.f));
        bfr[kc][1] = (short)f2bf(fmaxf(sC[ci][k0+1]+pa.y, 0.f));
        bfr[kc][2] = (short)f2bf(fmaxf(sC[ci][k0+2]+pa.z, 0.f));
        bfr[kc][3] = (short)f2bf(fmaxf(sC[ci][k0+3]+pa.w, 0.f));
        bfr[kc][4] = (short)f2bf(fmaxf(sC[ci][k0+4]+pb.x, 0.f));
        bfr[kc][5] = (short)f2bf(fmaxf(sC[ci][k0+5]+pb.y, 0.f));
        bfr[kc][6] = (short)f2bf(fmaxf(sC[ci][k0+6]+pb.z, 0.f));
        bfr[kc][7] = (short)f2bf(fmaxf(sC[ci][k0+7]+pb.w, 0.f));
      }
    }
    float sacc0 = 0.f, sacc1 = 0.f;
#pragma unroll
    for (int dt=0; dt<8; dt++){
      f4v a40 = {0.f,0.f,0.f,0.f};
      f4v a41 = {0.f,0.f,0.f,0.f};
#pragma unroll
      for (int kc=0;kc<4;kc++){
        s8v af = *(const s8v*)(sA2f + ((dt*4+kc)*64 + l)*8);
        a40 = __builtin_amdgcn_mfma_f32_16x16x32_bf16(af, bfr0[kc], a40, 0, 0, 0);
        a41 = __builtin_amdgcn_mfma_f32_16x16x32_bf16(af, bfr1[kc], a41, 0, 0, 0);
      }
      float4 a3v = *(const float4*)(A3 + dt*16 + kg*4);
      sacc0 += fmaxf(a40[0],0.f)*a3v.x + fmaxf(a40[1],0.f)*a3v.y
             + fmaxf(a40[2],0.f)*a3v.z + fmaxf(a40[3],0.f)*a3v.w;
      sacc1 += fmaxf(a41[0],0.f)*a3v.x + fmaxf(a41[1],0.f)*a3v.y
             + fmaxf(a41[2],0.f)*a3v.z + fmaxf(a41[3],0.f)*a3v.w;
    }
    sacc0 += __shfl_xor(sacc0, 16); sacc0 += __shfl_xor(sacc0, 32);
    sacc1 += __shfl_xor(sacc1, 16); sacc1 += __shfl_xor(sacc1, 32);
    if (l < 16){
      int c0 = (w*2+0)*16 + l;
      int c1 = (w*2+1)*16 + l;
      sSC[c0>>6][c0&63] = 1.f/(1.f + __expf(-sacc0));
      sSC[c1>>6][c1&63] = 1.f/(1.f + __expf(-sacc1));
    }
  }
  __syncthreads();

  if (w < 4){ // softmax: wave w -> b = blk*4 + w
    int b = blk*4 + w;
    int4 ra = *(const int4*)(R1g + (size_t)b*256 + l*4);
    float e0 = __expf(sSC[w][32 + ra.x]);
    float e1 = __expf(sSC[w][32 + ra.y]);
    float e2 = __expf(sSC[w][32 + ra.z]);
    float e3 = __expf(sSC[w][32 + ra.w]);
    float s = e0+e1+e2+e3;
    for (int m=1;m<64;m<<=1) s += __shfl_xor(s, m);
    float inv = 1.f/s;
    float4 o = { e0*inv, e1*inv, e2*inv, e3*inv };
    *(float4*)(W1g + (size_t)b*256 + l*4) = o;
    if (l < 16){
      float ee = __expf(sSC[w][R0g[b*16 + l]]);
      float s0 = ee;
      for (int m=1;m<16;m<<=1) s0 += __shfl_xor(s0, m);
      W0g[b*16 + l] = ee/s0;
    }
  }
}

// ---------------- weighted gathers v3: 8 waves/b, 2 rows/load, fp8
__global__ __launch_bounds__(512) void k_sv3(const int* __restrict__ E1g,
                                             const int* __restrict__ E2g,
                                             const float* __restrict__ W0g,
                                             const float* __restrict__ W1g,
                                             const unsigned short* __restrict__ entF,
                                             float* __restrict__ SV){
  int b = blockIdx.x, t = threadIdx.x, l = t&63, w = t>>6;
  __shared__ int sE1[16];
  __shared__ float sW0[16];
  __shared__ int sE2[256];
  __shared__ float sW1[256];
  __shared__ float sPart[8][128];
  if (t < 16){ sE1[t] = E1g[b*16+t]; sW0[t] = W0g[b*16+t]; }
  if (t >= 256){ int i = t-256; sE2[i] = E2g[b*256+i]; sW1[i] = W1g[b*256+i]; }
  __syncthreads();

  const unsigned* eF = (const unsigned*)entF;
  int half = l>>5, j = l&31;

  f4v a1 = {0.f,0.f,0.f,0.f};
#pragma unroll
  for (int i=0;i<16;i++){
    int row = w*32 + i*2 + half;
    float f = sW1[row];
    unsigned q = eF[(size_t)sE2[row]*32 + j];
    a1[0] += f*__builtin_amdgcn_cvt_f32_fp8((int)q, 0);
    a1[1] += f*__builtin_amdgcn_cvt_f32_fp8((int)q, 1);
    a1[2] += f*__builtin_amdgcn_cvt_f32_fp8((int)q, 2);
    a1[3] += f*__builtin_amdgcn_cvt_f32_fp8((int)q, 3);
  }
  f4v a0;
  {
    int row = w*2 + half;
    float f = sW0[row];
    unsigned q = eF[(size_t)sE1[row]*32 + j];
    a0[0] = f*__builtin_amdgcn_cvt_f32_fp8((int)q, 0);
    a0[1] = f*__builtin_amdgcn_cvt_f32_fp8((int)q, 1);
    a0[2] = f*__builtin_amdgcn_cvt_f32_fp8((int)q, 2);
    a0[3] = f*__builtin_amdgcn_cvt_f32_fp8((int)q, 3);
  }
#pragma unroll
  for (int r=0;r<4;r++){
    a1[r] += __shfl_xor(a1[r], 32);
    a0[r] += __shfl_xor(a0[r], 32);
  }
  if (half == 0) *(float4*)&sPart[w][j*4] = *(float4*)&a1;
  __syncthreads();
  if (t < 128){
    float s = 0.f;
#pragma unroll
    for (int ww=0;ww<8;ww++) s += sPart[ww][t];
    SV[((size_t)b*2 + 1)*128 + t] = s;
  }
  __syncthreads();
  if (half == 0) *(float4*)&sPart[w][j*4] = *(float4*)&a0;
  __syncthreads();
  if (t < 128){
    float s = 0.f;
#pragma unroll
    for (int ww=0;ww<8;ww++) s += sPart[ww][t];
    SV[((size_t)b*2 + 0)*128 + t] = s;
  }
}

// ---------------- MFMA vagg: 16-row tiles, grid (128, 2)
__global__ __launch_bounds__(256) void k_vagg2(const float* __restrict__ SV,
                                               const float* __restrict__ Hb,
                                               const float* __restrict__ S1,
                                               const unsigned short* __restrict__ WxF,
                                               const float* __restrict__ Wxb,
                                               const unsigned short* __restrict__ W1F,
                                               const float* __restrict__ W1b,
                                               const unsigned short* __restrict__ W2F,
                                               const float* __restrict__ W2b,
                                               float* __restrict__ out){
  int b0 = blockIdx.x * 16;
  int iter = blockIdx.y;
  int t = threadIdx.x, l = t&63, w = t>>6;
  __shared__ __align__(16) unsigned short sSV[16*128];
  __shared__ __align__(16) unsigned short sA [16*128];
  __shared__ __align__(16) unsigned short sV [16*256];
  char* sSVb = (char*)sSV; char* sAb = (char*)sA; char* sVb = (char*)sV;

  const float* anc = iter ? S1 : Hb;
  {
    int row = t>>4, c0 = (t&15)*8;
    const float* ps = SV + ((size_t)(b0+row)*2 + iter)*128 + c0;
    const float* pa = anc + (size_t)(b0+row)*128 + c0;
    int xo = (row&7)<<4;
#pragma unroll
    for (int c2=0;c2<4;c2++){
      float2 sv2 = *(const float2*)(ps + c2*2);
      float2 an2 = *(const float2*)(pa + c2*2);
      unsigned pv  = (unsigned)f2bf(sv2.x) | ((unsigned)f2bf(sv2.y)<<16);
      unsigned pan = (unsigned)f2bf(an2.x) | ((unsigned)f2bf(an2.y)<<16);
      int byte = (row*256 + c0*2 + c2*4) ^ xo;
      *(unsigned*)(sSVb + byte) = pv;
      *(unsigned*)(sAb  + byte) = pan;
    }
  }
  __syncthreads();

  int kl = l&15, kg = l>>4;
  {
    int rowg = kl;
    int xo = (rowg&7)<<4;
    s8v af[4];
#pragma unroll
    for (int kc=0;kc<4;kc++)
      af[kc] = *(const s8v*)(sSVb + ((rowg*256 + kc*64 + kg*16) ^ xo));
#pragma unroll
    for (int nt4=0;nt4<4;nt4++){
      int ntg = w*4 + nt4;
      int n = ntg*16 + kl;
      float bias = Wxb[iter*256 + n];
      f4v acc = {bias,bias,bias,bias};
#pragma unroll
      for (int kc=0;kc<4;kc++){
        s8v bf = *(const s8v*)(WxF + ((size_t)(((iter*16 + ntg)*4 + kc)*64 + l))*8);
        acc = __builtin_amdgcn_mfma_f32_16x16x32_bf16(af[kc], bf, acc, 0, 0, 0);
      }
#pragma unroll
      for (int r=0;r<4;r++){
        int rowl = kg*4 + r;
        int byte = (rowl*512 + n*2) ^ ((rowl&7)<<4);
        *(unsigned short*)(sVb + byte) = f2bf(leakyf(acc[r]));
      }
    }
  }
  __syncthreads();
  {
    int rowl = kl;
    int xo = (rowl&7)<<4;
    s8v x1f[8], x2f[8];
#pragma unroll
    for (int kc=0;kc<8;kc++){
      int k0 = kc*32 + kg*8;
      s8v vv = *(const s8v*)(sVb + ((rowl*512 + k0*2) ^ xo));
      s8v aa = *(const s8v*)(sAb + ((rowl*256 + (k0&127)*2) ^ xo));
#pragma unroll
      for (int j=0;j<8;j++){
        float vf = bf2f((unsigned short)vv[j]);
        float av = bf2f((unsigned short)aa[j]);
        x1f[kc][j] = (short)f2bf(av + vf);
        x2f[kc][j] = (short)f2bf(av * vf);
      }
    }
    int obase = iter ? 0 : 256;
#pragma unroll
    for (int nt4=0;nt4<4;nt4++){
      int ntg = w*4 + nt4;
      int n = ntg*16 + kl;
      float bb1 = W1b[n], bb2 = W2b[n];
      f4v a1 = {bb1,bb1,bb1,bb1};
      f4v a2 = {bb2,bb2,bb2,bb2};
#pragma unroll
      for (int kc=0;kc<8;kc++){
        s8v wf1 = *(const s8v*)(W1F + ((size_t)((ntg*8 + kc)*64 + l))*8);
        a1 = __builtin_amdgcn_mfma_f32_16x16x32_bf16(x1f[kc], wf1, a1, 0, 0, 0);
      }
#pragma unroll
      for (int kc=0;kc<8;kc++){
        s8v wf2 = *(const s8v*)(W2F + ((size_t)((ntg*8 + kc)*64 + l))*8);
        a2 = __builtin_amdgcn_mfma_f32_16x16x32_bf16(x2f[kc], wf2, a2, 0, 0, 0);
      }
#pragma unroll
      for (int r=0;r<4;r++){
        int row = kg*4 + r;
        out[(size_t)(b0+row)*640 + obase + n] = leakyf(a1[r]) + leakyf(a2[r]);
      }
    }
  }
}

extern "C" void kernel_launch(void* const* d_in, const int* in_sizes, int n_in,
                              void* d_out, int out_size, void* d_ws, size_t ws_size,
                              hipStream_t stream) {
  const int*   eidx = (const int*)d_in[0];
  const int*   adjE = (const int*)d_in[1];
  const int*   adjR = (const int*)d_in[2];
  const float* ent  = (const float*)d_in[3];
  const float* rel  = (const float*)d_in[4];
  const float* A1   = (const float*)d_in[5];
  const float* A2   = (const float*)d_in[6];
  const float* A3   = (const float*)d_in[7];
  const float* Wxw  = (const float*)d_in[8];
  const float* Wxb  = (const float*)d_in[9];
  const float* W1w  = (const float*)d_in[10];
  const float* W1b  = (const float*)d_in[11];
  const float* W2w  = (const float*)d_in[12];
  const float* W2b  = (const float*)d_in[13];
  float* out = (float*)d_out;

  char* wsb = (char*)d_ws;
  size_t off = 0;
  auto alloc = [&](size_t bytes)->char*{
    char* p = wsb + off; off += (bytes + 255) & ~(size_t)255; return p;
  };
  float* Pg   = (float*)alloc(NREL*DIM*4);
  unsigned short* A1Lf = (unsigned short*)alloc(2048*8*2);
  unsigned short* A2f  = (unsigned short*)alloc(2048*8*2);
  unsigned short* WxF = (unsigned short*)alloc((size_t)8192*8*2);
  unsigned short* W1F = (unsigned short*)alloc((size_t)8192*8*2);
  unsigned short* W2F = (unsigned short*)alloc((size_t)8192*8*2);
  unsigned short* entF = (unsigned short*)alloc((size_t)NENT*64*2);
  unsigned* ANb  = (unsigned*)alloc((size_t)NB*2*64*4);
  float* Hb = (float*)alloc((size_t)NB*DIM*4);
  float* S1 = (float*)alloc((size_t)NB*DIM*4);
  float* SV = (float*)alloc((size_t)NB*2*DIM*4);
  int* E1g = (int*)alloc((size_t)NB*16*4);
  int* E2g = (int*)alloc((size_t)NB*256*4);
  int* R0g = (int*)alloc((size_t)NB*16*4);
  int* R1g = (int*)alloc((size_t)NB*256*4);
  float* W0g = (float*)alloc((size_t)NB*16*4);
  float* W1g = (float*)alloc((size_t)NB*256*4);

  k_gathprep<<<dim3(GATH_BLKS + 144), dim3(256), 0, stream>>>(
      eidx, adjE, adjR, ent, rel, A1, A2, Wxw, W1w, W2w,
      Pg, A1Lf, A2f, WxF, W1F, W2F,
      E1g, E2g, R0g, R1g, ANb, Hb, S1, out);
  k_scorescale<<<dim3(SCORE_BLKS + SCALE_BLKS), dim3(512), 0, stream>>>(
      ANb, A1Lf, Pg, A2f, A3, R0g, R1g, ent, entF, W0g, W1g);
  k_sv3 <<<dim3(NB),     dim3(512), 0, stream>>>(E1g, E2g, W0g, W1g, entF, SV);
  k_vagg2<<<dim3(NB/16, 2), dim3(256), 0, stream>>>(SV, Hb, S1, WxF, Wxb,
                                                    W1F, W1b, W2F, W2b, out);
}

// Round 16
// 58.153 us; speedup vs baseline: 1.2165x; 1.2165x over previous
//
#include <hip/hip_runtime.h>

#define NENT 100000
#define NREL 32
#define DIM  128
#define NB   2048

typedef short s8v __attribute__((ext_vector_type(8)));
typedef float f4v __attribute__((ext_vector_type(4)));
typedef unsigned u4v __attribute__((ext_vector_type(4)));

__device__ __forceinline__ unsigned short f2bf(float x){
  unsigned u = __float_as_uint(x);
  return (unsigned short)((u + 0x7fffu + ((u>>16)&1u)) >> 16);
}
__device__ __forceinline__ float bf2f(unsigned short u){
  return __uint_as_float(((unsigned)u) << 16);
}
__device__ __forceinline__ float lo2f(unsigned p){ return __uint_as_float(p << 16); }
__device__ __forceinline__ float hi2f(unsigned p){ return __uint_as_float(p & 0xffff0000u); }
__device__ __forceinline__ float leakyf(float x){ return x > 0.f ? x : 0.2f*x; }
__device__ __forceinline__ unsigned pkbf(float a, float b){
  unsigned r;
  asm("v_cvt_pk_bf16_f32 %0, %1, %2" : "=v"(r) : "v"(a), "v"(b));
  return r;
}

#define GATH_BLKS  512
#define SCALE_BLKS 12500   // 8 rows per 256-thr block, 4 dims/lane

// ---------------- initgath: gath (raw-ent renorm) ∥ scale→entF ∥ prep — no cross-block deps
__global__ __launch_bounds__(256) void k_initgath(const int* __restrict__ eidx,
                                                  const int* __restrict__ adjE,
                                                  const int* __restrict__ adjR,
                                                  const float* __restrict__ ent,
                                                  const float* __restrict__ rel,
                                                  const float* __restrict__ A1,
                                                  const float* __restrict__ A2,
                                                  const float* __restrict__ Wxw,
                                                  const float* __restrict__ W1w,
                                                  const float* __restrict__ W2w,
                                                  unsigned short* __restrict__ entF,
                                                  float* __restrict__ Pg,
                                                  unsigned short* __restrict__ A1Lf,
                                                  unsigned short* __restrict__ A2f,
                                                  unsigned short* __restrict__ WxF,
                                                  unsigned short* __restrict__ W1F,
                                                  unsigned short* __restrict__ W2F,
                                                  int* __restrict__ E1g, int* __restrict__ E2g,
                                                  int* __restrict__ R0g, int* __restrict__ R1g,
                                                  unsigned* __restrict__ ANb,
                                                  float* __restrict__ Hb, float* __restrict__ S1,
                                                  float* __restrict__ out){
  int t = threadIdx.x;
  __shared__ float srn[2][128];
  __shared__ float red[2][2];
  if (blockIdx.x < GATH_BLKS){
    // ---- gather: wave w -> b = blk*4 + w ; barrier-free, raw-ent renorm
    int w = t>>6, l = t&63;
    int b = blockIdx.x*4 + w;
    int idx = eidx[b];
    int e1 = 0;
    if (l < 16){
      e1 = adjE[idx*16 + l];
      E1g[b*16+l] = e1;
      R0g[b*16+l] = adjR[idx*16 + l];
    }
    int esrc = __shfl(e1, l>>2);
    int4 e2 = *(const int4*)(adjE + (size_t)esrc*16 + (l&3)*4);
    int4 r1 = *(const int4*)(adjR + (size_t)esrc*16 + (l&3)*4);
    *(int4*)(E2g + (size_t)b*256 + l*4) = e2;
    *(int4*)(R1g + (size_t)b*256 + l*4) = r1;
    // batch-issue all 17 row loads, then reduce
    float2 hv = *(const float2*)(ent + (size_t)idx*128 + 2*l);
    float2 rv[16];
#pragma unroll
    for (int i=0;i<16;i++){
      int e = __shfl(e1, i);
      rv[i] = *(const float2*)(ent + (size_t)e*128 + 2*l);
    }
    float ssh = hv.x*hv.x + hv.y*hv.y;
    for (int m=1;m<64;m<<=1) ssh += __shfl_xor(ssh, m);
    float sch = fminf(1.f, 1.f/(sqrtf(ssh) + 1e-7f));
    hv.x *= sch; hv.y *= sch;
    float sx = 0.f, sy = 0.f;
#pragma unroll
    for (int i=0;i<16;i++){
      float ss = rv[i].x*rv[i].x + rv[i].y*rv[i].y;
      for (int m=1;m<64;m<<=1) ss += __shfl_xor(ss, m);
      float sc = fminf(1.f, 1.f/(sqrtf(ss) + 1e-7f));
      sx += sc*rv[i].x; sy += sc*rv[i].y;
    }
    ANb[((size_t)b*2 + 0)*64 + l] = (unsigned)f2bf(hv.x) | ((unsigned)f2bf(hv.y) << 16);
    ANb[((size_t)b*2 + 1)*64 + l] = (unsigned)f2bf(sx) | ((unsigned)f2bf(sy) << 16);
    *(float2*)(Hb + (size_t)b*128 + 2*l) = hv;
    *(float2*)(out + (size_t)b*640 + 512 + 2*l) = hv;
    float2 sv = { sx, sy };
    *(float2*)(S1 + (size_t)b*128 + 2*l) = sv;
    return;
  }
  if (blockIdx.x < GATH_BLKS + SCALE_BLKS){
    // ---- scan: 8 rows/block, 4 dims/lane (float4 + 2×cvt_pk_fp8 + uint store)
    int blkS = blockIdx.x - GATH_BLKS;
    int w = t>>6, l = t&63;
    int half = l>>5, j = l&31;
    int row = blkS*8 + w*2 + half;
    if (row >= NENT) return;
    float4 v = *(const float4*)(ent + (size_t)row*128 + 4*j);
    float ss = v.x*v.x + v.y*v.y + v.z*v.z + v.w*v.w;
    for (int m=1;m<32;m<<=1) ss += __shfl_xor(ss, m);
    float sc = fminf(1.f, 1.f/(sqrtf(ss) + 1e-7f));
    int p = __builtin_amdgcn_cvt_pk_fp8_f32(sc*v.x, sc*v.y, 0, false);
    p = __builtin_amdgcn_cvt_pk_fp8_f32(sc*v.z, sc*v.w, p, true);
    ((unsigned*)entF)[(size_t)row*32 + j] = (unsigned)p;
    return;
  }
  int half = t>>7, tt = t&127;
  int blk = (blockIdx.x - GATH_BLKS - SCALE_BLKS)*2 + half;
  if (blk < 32){
    int r = blk;
    float v = rel[r*128 + tt];
    float ss = v*v;
    for (int m=1;m<64;m<<=1) ss += __shfl_xor(ss, m);
    if ((tt&63)==0) red[half][tt>>6] = ss;
    __syncthreads();
    float nrm = sqrtf(red[half][0]+red[half][1]);
    float f = fminf(1.f, 1.f/(nrm + 1e-7f));
    srn[half][tt] = v*f;
    __syncthreads();
    const float4* ar = (const float4*)(A1 + tt*256 + 128);
    float acc = 0.f;
#pragma unroll
    for (int k4=0;k4<32;k4++){
      float4 a = ar[k4];
      acc += a.x*srn[half][k4*4] + a.y*srn[half][k4*4+1]
           + a.z*srn[half][k4*4+2] + a.w*srn[half][k4*4+3];
    }
    Pg[r*128 + tt] = acc;
  } else if (blk < 64){
    int bb = blk - 32;
    int fid = bb*64 + (tt>>1);
    int hf = tt&1;
    int lane = fid & 63, kc = (fid>>6)&3, dt = fid>>8;
    int d = dt*16 + (lane&15);
    int kb = kc*32 + ((lane>>4)&3)*8 + hf*4;
#pragma unroll
    for (int i=0;i<4;i++)
      A2f[fid*8 + hf*4 + i] = f2bf(A2[d*128 + kb + i]);
  } else if (blk < 96){
    int bb = blk - 64;
    int fid = bb*64 + (tt>>1);
    int hf = tt&1;
    int lane = fid & 63, kc = (fid>>6)&3, dt = fid>>8;
    int d = dt*16 + (lane&15);
    int kb = kc*32 + ((lane>>4)&3)*8 + hf*4;
#pragma unroll
    for (int i=0;i<4;i++)
      A1Lf[fid*8 + hf*4 + i] = f2bf(A1[d*256 + kb + i]);
  } else if (blk < 160){
    int fid = (blk-96)*128 + tt;
    int l = fid&63, kc = (fid>>6)&3, nt = (fid>>8)&15, iter = (fid>>12)&1;
    int n = nt*16 + (l&15);
    int k = kc*32 + ((l>>4)&3)*8;
    const float* src = Wxw + ((size_t)((iter*2 + (n>>7))*128 + (n&127)))*128 + k;
#pragma unroll
    for (int j=0;j<8;j++) WxF[(size_t)fid*8 + j] = f2bf(src[j]);
  } else if (blk < 224){
    int fid = (blk-160)*128 + tt;
    int l = fid&63, kc = (fid>>6)&7, nt = (fid>>9)&15;
    int n = nt*16 + (l&15);
    int k = kc*32 + ((l>>4)&3)*8;
#pragma unroll
    for (int j=0;j<8;j++) W1F[(size_t)fid*8 + j] = f2bf(W1w[(size_t)n*256 + k + j]);
  } else {
    int fid = (blk-224)*128 + tt;
    int l = fid&63, kc = (fid>>6)&7, nt = (fid>>9)&15;
    int n = nt*16 + (l&15);
    int k = kc*32 + ((l>>4)&3)*8;
#pragma unroll
    for (int j=0;j<8;j++) W2F[(size_t)fid*8 + j] = f2bf(W2w[(size_t)n*256 + k + j]);
  }
}

// ---------------- batched scores: 4 b/block, 8 waves, A2f LDS-staged, cvt_pk B-frags
__global__ __launch_bounds__(512) void k_score2(const unsigned* __restrict__ ANb,
                                                const unsigned short* __restrict__ A1Lf,
                                                const float* __restrict__ Pg,
                                                const unsigned short* __restrict__ A2f,
                                                const float* __restrict__ A3,
                                                const int* __restrict__ R0g,
                                                const int* __restrict__ R1g,
                                                float* __restrict__ W0g,
                                                float* __restrict__ W1g){
  int blk = blockIdx.x;              // 4 b per block
  int t = threadIdx.x, l = t&63, w = t>>6;   // 8 waves
  __shared__ __align__(16) unsigned short sA2f[2048*8];  // 32 KB
  __shared__ __align__(16) unsigned sAN[16*64];          // 8 anchors (rows 8..15 zero), swizzled
  __shared__ float sC[8][132];
  __shared__ float sSC[4][64];

  { // stage A2f (32 KB, 4 uint4/thread) + anchors
    const uint4* src = (const uint4*)A2f;
    uint4* dst = (uint4*)sA2f;
#pragma unroll
    for (int i=0;i<4;i++) dst[t + i*512] = src[t + i*512];
    if (t < 256){
      int row = t>>4, seg = t&15;
      uint4 v = {0u,0u,0u,0u};
      if (row < 8) v = *(const uint4*)(ANb + ((size_t)blk*8 + row)*64 + seg*4);
      *(uint4*)((char*)sAN + ((row*256 + seg*16) ^ ((row&7)<<4))) = v;
    }
  }
  __syncthreads();

  int cl = l&15, kg = l>>4;
  { // G1: c = A1L @ anchors ; wave w -> dt = w
    s8v bf[4];
#pragma unroll
    for (int kc=0;kc<4;kc++)
      bf[kc] = *(const s8v*)((const char*)sAN + ((cl*256 + (kc*32+kg*8)*2) ^ ((cl&7)<<4)));
    int dt = w;
    f4v acc = {0.f,0.f,0.f,0.f};
#pragma unroll
    for (int kc=0;kc<4;kc++){
      s8v af = *(const s8v*)(A1Lf + ((size_t)((dt*4+kc)*64 + l))*8);
      acc = __builtin_amdgcn_mfma_f32_16x16x32_bf16(af, bf[kc], acc, 0, 0, 0);
    }
    if (cl < 8){
#pragma unroll
      for (int r=0;r<4;r++) sC[cl][dt*16 + kg*4 + r] = acc[r];
    }
  }
  __syncthreads();

  { // G2: wave w -> anchor ci = w ; cc splits relations (rr = cc*16+cl)
    s8v bfr0[4], bfr1[4];
#pragma unroll
    for (int cc=0; cc<2; cc++){
      int ci = w;
      int rr = cc*16 + cl;
      s8v* bfr = cc ? bfr1 : bfr0;
#pragma unroll
      for (int kc=0;kc<4;kc++){
        int k0 = kc*32 + kg*8;
        float4 pa = *(const float4*)(Pg + rr*128 + k0);
        float4 pb = *(const float4*)(Pg + rr*128 + k0 + 4);
        unsigned u0 = pkbf(fmaxf(sC[ci][k0+0]+pa.x, 0.f), fmaxf(sC[ci][k0+1]+pa.y, 0.f));
        unsigned u1 = pkbf(fmaxf(sC[ci][k0+2]+pa.z, 0.f), fmaxf(sC[ci][k0+3]+pa.w, 0.f));
        unsigned u2 = pkbf(fmaxf(sC[ci][k0+4]+pb.x, 0.f), fmaxf(sC[ci][k0+5]+pb.y, 0.f));
        unsigned u3 = pkbf(fmaxf(sC[ci][k0+6]+pb.z, 0.f), fmaxf(sC[ci][k0+7]+pb.w, 0.f));
        union { u4v u; s8v s; } x;
        x.u[0] = u0; x.u[1] = u1; x.u[2] = u2; x.u[3] = u3;
        bfr[kc] = x.s;
      }
    }
    float sacc0 = 0.f, sacc1 = 0.f;
#pragma unroll
    for (int dt=0; dt<8; dt++){
      f4v a40 = {0.f,0.f,0.f,0.f};
      f4v a41 = {0.f,0.f,0.f,0.f};
#pragma unroll
      for (int kc=0;kc<4;kc++){
        s8v af = *(const s8v*)(sA2f + ((dt*4+kc)*64 + l)*8);
        a40 = __builtin_amdgcn_mfma_f32_16x16x32_bf16(af, bfr0[kc], a40, 0, 0, 0);
        a41 = __builtin_amdgcn_mfma_f32_16x16x32_bf16(af, bfr1[kc], a41, 0, 0, 0);
      }
      float4 a3v = *(const float4*)(A3 + dt*16 + kg*4);
      sacc0 += fmaxf(a40[0],0.f)*a3v.x + fmaxf(a40[1],0.f)*a3v.y
             + fmaxf(a40[2],0.f)*a3v.z + fmaxf(a40[3],0.f)*a3v.w;
      sacc1 += fmaxf(a41[0],0.f)*a3v.x + fmaxf(a41[1],0.f)*a3v.y
             + fmaxf(a41[2],0.f)*a3v.z + fmaxf(a41[3],0.f)*a3v.w;
    }
    sacc0 += __shfl_xor(sacc0, 16); sacc0 += __shfl_xor(sacc0, 32);
    sacc1 += __shfl_xor(sacc1, 16); sacc1 += __shfl_xor(sacc1, 32);
    if (l < 16){
      int c0 = (w*2+0)*16 + l;
      int c1 = (w*2+1)*16 + l;
      sSC[c0>>6][c0&63] = 1.f/(1.f + __expf(-sacc0));
      sSC[c1>>6][c1&63] = 1.f/(1.f + __expf(-sacc1));
    }
  }
  __syncthreads();

  if (w < 4){ // softmax: wave w -> b = blk*4 + w
    int b = blk*4 + w;
    int4 ra = *(const int4*)(R1g + (size_t)b*256 + l*4);
    float e0 = __expf(sSC[w][32 + ra.x]);
    float e1 = __expf(sSC[w][32 + ra.y]);
    float e2 = __expf(sSC[w][32 + ra.z]);
    float e3 = __expf(sSC[w][32 + ra.w]);
    float s = e0+e1+e2+e3;
    for (int m=1;m<64;m<<=1) s += __shfl_xor(s, m);
    float inv = 1.f/s;
    float4 o = { e0*inv, e1*inv, e2*inv, e3*inv };
    *(float4*)(W1g + (size_t)b*256 + l*4) = o;
    if (l < 16){
      float ee = __expf(sSC[w][R0g[b*16 + l]]);
      float s0 = ee;
      for (int m=1;m<16;m<<=1) s0 += __shfl_xor(s0, m);
      W0g[b*16 + l] = ee/s0;
    }
  }
}

// ---------------- weighted gathers v3: 8 waves/b, 2 rows/load, fp8
__global__ __launch_bounds__(512) void k_sv3(const int* __restrict__ E1g,
                                             const int* __restrict__ E2g,
                                             const float* __restrict__ W0g,
                                             const float* __restrict__ W1g,
                                             const unsigned short* __restrict__ entF,
                                             float* __restrict__ SV){
  int b = blockIdx.x, t = threadIdx.x, l = t&63, w = t>>6;
  __shared__ int sE1[16];
  __shared__ float sW0[16];
  __shared__ int sE2[256];
  __shared__ float sW1[256];
  __shared__ float sPart[8][128];
  if (t < 16){ sE1[t] = E1g[b*16+t]; sW0[t] = W0g[b*16+t]; }
  if (t >= 256){ int i = t-256; sE2[i] = E2g[b*256+i]; sW1[i] = W1g[b*256+i]; }
  __syncthreads();

  const unsigned* eF = (const unsigned*)entF;
  int half = l>>5, j = l&31;

  f4v a1 = {0.f,0.f,0.f,0.f};
#pragma unroll
  for (int i=0;i<16;i++){
    int row = w*32 + i*2 + half;
    float f = sW1[row];
    unsigned q = eF[(size_t)sE2[row]*32 + j];
    a1[0] += f*__builtin_amdgcn_cvt_f32_fp8((int)q, 0);
    a1[1] += f*__builtin_amdgcn_cvt_f32_fp8((int)q, 1);
    a1[2] += f*__builtin_amdgcn_cvt_f32_fp8((int)q, 2);
    a1[3] += f*__builtin_amdgcn_cvt_f32_fp8((int)q, 3);
  }
  f4v a0;
  {
    int row = w*2 + half;
    float f = sW0[row];
    unsigned q = eF[(size_t)sE1[row]*32 + j];
    a0[0] = f*__builtin_amdgcn_cvt_f32_fp8((int)q, 0);
    a0[1] = f*__builtin_amdgcn_cvt_f32_fp8((int)q, 1);
    a0[2] = f*__builtin_amdgcn_cvt_f32_fp8((int)q, 2);
    a0[3] = f*__builtin_amdgcn_cvt_f32_fp8((int)q, 3);
  }
#pragma unroll
  for (int r=0;r<4;r++){
    a1[r] += __shfl_xor(a1[r], 32);
    a0[r] += __shfl_xor(a0[r], 32);
  }
  if (half == 0) *(float4*)&sPart[w][j*4] = *(float4*)&a1;
  __syncthreads();
  if (t < 128){
    float s = 0.f;
#pragma unroll
    for (int ww=0;ww<8;ww++) s += sPart[ww][t];
    SV[((size_t)b*2 + 1)*128 + t] = s;
  }
  __syncthreads();
  if (half == 0) *(float4*)&sPart[w][j*4] = *(float4*)&a0;
  __syncthreads();
  if (t < 128){
    float s = 0.f;
#pragma unroll
    for (int ww=0;ww<8;ww++) s += sPart[ww][t];
    SV[((size_t)b*2 + 0)*128 + t] = s;
  }
}

// ---------------- MFMA vagg: 16-row tiles, grid (128, 2)
__global__ __launch_bounds__(256) void k_vagg2(const float* __restrict__ SV,
                                               const float* __restrict__ Hb,
                                               const float* __restrict__ S1,
                                               const unsigned short* __restrict__ WxF,
                                               const float* __restrict__ Wxb,
                                               const unsigned short* __restrict__ W1F,
                                               const float* __restrict__ W1b,
                                               const unsigned short* __restrict__ W2F,
                                               const float* __restrict__ W2b,
                                               float* __restrict__ out){
  int b0 = blockIdx.x * 16;
  int iter = blockIdx.y;
  int t = threadIdx.x, l = t&63, w = t>>6;
  __shared__ __align__(16) unsigned short sSV[16*128];
  __shared__ __align__(16) unsigned short sA [16*128];
  __shared__ __align__(16) unsigned short sV [16*256];
  char* sSVb = (char*)sSV; char* sAb = (char*)sA; char* sVb = (char*)sV;

  const float* anc = iter ? S1 : Hb;
  {
    int row = t>>4, c0 = (t&15)*8;
    const float* ps = SV + ((size_t)(b0+row)*2 + iter)*128 + c0;
    const float* pa = anc + (size_t)(b0+row)*128 + c0;
    int xo = (row&7)<<4;
#pragma unroll
    for (int c2=0;c2<4;c2++){
      float2 sv2 = *(const float2*)(ps + c2*2);
      float2 an2 = *(const float2*)(pa + c2*2);
      unsigned pv  = (unsigned)f2bf(sv2.x) | ((unsigned)f2bf(sv2.y)<<16);
      unsigned pan = (unsigned)f2bf(an2.x) | ((unsigned)f2bf(an2.y)<<16);
      int byte = (row*256 + c0*2 + c2*4) ^ xo;
      *(unsigned*)(sSVb + byte) = pv;
      *(unsigned*)(sAb  + byte) = pan;
    }
  }
  __syncthreads();

  int kl = l&15, kg = l>>4;
  {
    int rowg = kl;
    int xo = (rowg&7)<<4;
    s8v af[4];
#pragma unroll
    for (int kc=0;kc<4;kc++)
      af[kc] = *(const s8v*)(sSVb + ((rowg*256 + kc*64 + kg*16) ^ xo));
#pragma unroll
    for (int nt4=0;nt4<4;nt4++){
      int ntg = w*4 + nt4;
      int n = ntg*16 + kl;
      float bias = Wxb[iter*256 + n];
      f4v acc = {bias,bias,bias,bias};
#pragma unroll
      for (int kc=0;kc<4;kc++){
        s8v bf = *(const s8v*)(WxF + ((size_t)(((iter*16 + ntg)*4 + kc)*64 + l))*8);
        acc = __builtin_amdgcn_mfma_f32_16x16x32_bf16(af[kc], bf, acc, 0, 0, 0);
      }
#pragma unroll
      for (int r=0;r<4;r++){
        int rowl = kg*4 + r;
        int byte = (rowl*512 + n*2) ^ ((rowl&7)<<4);
        *(unsigned short*)(sVb + byte) = f2bf(leakyf(acc[r]));
      }
    }
  }
  __syncthreads();
  {
    int rowl = kl;
    int xo = (rowl&7)<<4;
    s8v x1f[8], x2f[8];
#pragma unroll
    for (int kc=0;kc<8;kc++){
      int k0 = kc*32 + kg*8;
      s8v vv = *(const s8v*)(sVb + ((rowl*512 + k0*2) ^ xo));
      s8v aa = *(const s8v*)(sAb + ((rowl*256 + (k0&127)*2) ^ xo));
#pragma unroll
      for (int j=0;j<8;j++){
        float vf = bf2f((unsigned short)vv[j]);
        float av = bf2f((unsigned short)aa[j]);
        x1f[kc][j] = (short)f2bf(av + vf);
        x2f[kc][j] = (short)f2bf(av * vf);
      }
    }
    int obase = iter ? 0 : 256;
#pragma unroll
    for (int nt4=0;nt4<4;nt4++){
      int ntg = w*4 + nt4;
      int n = ntg*16 + kl;
      float bb1 = W1b[n], bb2 = W2b[n];
      f4v a1 = {bb1,bb1,bb1,bb1};
      f4v a2 = {bb2,bb2,bb2,bb2};
#pragma unroll
      for (int kc=0;kc<8;kc++){
        s8v wf1 = *(const s8v*)(W1F + ((size_t)((ntg*8 + kc)*64 + l))*8);
        a1 = __builtin_amdgcn_mfma_f32_16x16x32_bf16(x1f[kc], wf1, a1, 0, 0, 0);
      }
#pragma unroll
      for (int kc=0;kc<8;kc++){
        s8v wf2 = *(const s8v*)(W2F + ((size_t)((ntg*8 + kc)*64 + l))*8);
        a2 = __builtin_amdgcn_mfma_f32_16x16x32_bf16(x2f[kc], wf2, a2, 0, 0, 0);
      }
#pragma unroll
      for (int r=0;r<4;r++){
        int row = kg*4 + r;
        out[(size_t)(b0+row)*640 + obase + n] = leakyf(a1[r]) + leakyf(a2[r]);
      }
    }
  }
}

extern "C" void kernel_launch(void* const* d_in, const int* in_sizes, int n_in,
                              void* d_out, int out_size, void* d_ws, size_t ws_size,
                              hipStream_t stream) {
  const int*   eidx = (const int*)d_in[0];
  const int*   adjE = (const int*)d_in[1];
  const int*   adjR = (const int*)d_in[2];
  const float* ent  = (const float*)d_in[3];
  const float* rel  = (const float*)d_in[4];
  const float* A1   = (const float*)d_in[5];
  const float* A2   = (const float*)d_in[6];
  const float* A3   = (const float*)d_in[7];
  const float* Wxw  = (const float*)d_in[8];
  const float* Wxb  = (const float*)d_in[9];
  const float* W1w  = (const float*)d_in[10];
  const float* W1b  = (const float*)d_in[11];
  const float* W2w  = (const float*)d_in[12];
  const float* W2b  = (const float*)d_in[13];
  float* out = (float*)d_out;

  char* wsb = (char*)d_ws;
  size_t off = 0;
  auto alloc = [&](size_t bytes)->char*{
    char* p = wsb + off; off += (bytes + 255) & ~(size_t)255; return p;
  };
  float* Pg   = (float*)alloc(NREL*DIM*4);
  unsigned short* A1Lf = (unsigned short*)alloc(2048*8*2);
  unsigned short* A2f  = (unsigned short*)alloc(2048*8*2);
  unsigned short* WxF = (unsigned short*)alloc((size_t)8192*8*2);
  unsigned short* W1F = (unsigned short*)alloc((size_t)8192*8*2);
  unsigned short* W2F = (unsigned short*)alloc((size_t)8192*8*2);
  unsigned short* entF = (unsigned short*)alloc((size_t)NENT*64*2);
  unsigned* ANb  = (unsigned*)alloc((size_t)NB*2*64*4);
  float* Hb = (float*)alloc((size_t)NB*DIM*4);
  float* S1 = (float*)alloc((size_t)NB*DIM*4);
  float* SV = (float*)alloc((size_t)NB*2*DIM*4);
  int* E1g = (int*)alloc((size_t)NB*16*4);
  int* E2g = (int*)alloc((size_t)NB*256*4);
  int* R0g = (int*)alloc((size_t)NB*16*4);
  int* R1g = (int*)alloc((size_t)NB*256*4);
  float* W0g = (float*)alloc((size_t)NB*16*4);
  float* W1g = (float*)alloc((size_t)NB*256*4);

  k_initgath<<<dim3(GATH_BLKS + SCALE_BLKS + 144), dim3(256), 0, stream>>>(
      eidx, adjE, adjR, ent, rel, A1, A2, Wxw, W1w, W2w,
      entF, Pg, A1Lf, A2f, WxF, W1F, W2F,
      E1g, E2g, R0g, R1g, ANb, Hb, S1, out);
  k_score2<<<dim3(NB/4), dim3(512), 0, stream>>>(ANb, A1Lf, Pg, A2f, A3,
                                                 R0g, R1g, W0g, W1g);
  k_sv3 <<<dim3(NB),     dim3(512), 0, stream>>>(E1g, E2g, W0g, W1g, entF, SV);
  k_vagg2<<<dim3(NB/16, 2), dim3(256), 0, stream>>>(SV, Hb, S1, WxF, Wxb,
                                                    W1F, W1b, W2F, W2b, out);
}